// Round 9
// baseline (667.054 us; speedup 1.0000x reference)
//
#include <hip/hip_runtime.h>
#include <math.h>

// Problem constants
constexpr int Bb = 2, Ss = 2048, Dd = 1024, Hh = 16, HDd = 64;

typedef __attribute__((ext_vector_type(8))) short bf16x8;     // MFMA A/B frag
typedef __attribute__((ext_vector_type(4))) float f32x4;      // MFMA C/D frag
typedef __attribute__((ext_vector_type(8))) unsigned short u16x8;
typedef __attribute__((ext_vector_type(4))) unsigned short u16x4;

__device__ __forceinline__ unsigned short bf16_rn(float f) {
  unsigned int u = __float_as_uint(f);
  u += 0x7fffu + ((u >> 16) & 1u);
  return (unsigned short)(u >> 16);
}
__device__ __forceinline__ float bf16_f(unsigned short h) {
  return __uint_as_float(((unsigned int)h) << 16);
}

// ---------------------------------------------------------------------------
// split fp32 array into hi/lo bf16 arrays
// ---------------------------------------------------------------------------
__global__ __launch_bounds__(256) void split_f32(
    const float* __restrict__ in, unsigned short* __restrict__ hi,
    unsigned short* __restrict__ lo, int n8) {
  int i = blockIdx.x * 256 + threadIdx.x;
  if (i >= n8) return;
  const float4* p = (const float4*)in + (size_t)i * 2;
  float4 a = p[0], b = p[1];
  float v[8] = {a.x, a.y, a.z, a.w, b.x, b.y, b.z, b.w};
  u16x8 h, l;
  #pragma unroll
  for (int j = 0; j < 8; j++) {
    unsigned short hb = bf16_rn(v[j]);
    h[j] = hb;
    l[j] = bf16_rn(v[j] - bf16_f(hb));
  }
  *(u16x8*)(hi + (size_t)i * 8) = h;
  *(u16x8*)(lo + (size_t)i * 8) = l;
}

// transpose W[K][N] -> Wt[N][K], split into hi/lo bf16
__global__ __launch_bounds__(256) void transpose_split_f32(
    const float* __restrict__ W, unsigned short* __restrict__ Thi,
    unsigned short* __restrict__ Tlo, int K, int N) {
  __shared__ float tile[32][33];
  int n0 = blockIdx.x * 32, k0 = blockIdx.y * 32;
  int t = threadIdx.x;
  #pragma unroll
  for (int p = 0; p < 4; p++) {
    int idx = t + p * 256;
    int kk = idx >> 5, nn = idx & 31;
    tile[kk][nn] = W[(size_t)(k0 + kk) * N + n0 + nn];
  }
  __syncthreads();
  #pragma unroll
  for (int p = 0; p < 4; p++) {
    int idx = t + p * 256;
    int nn = idx >> 5, kk = idx & 31;
    float v = tile[kk][nn];
    unsigned short hb = bf16_rn(v);
    size_t o = (size_t)(n0 + nn) * K + k0 + kk;
    Thi[o] = hb;
    Tlo[o] = bf16_rn(v - bf16_f(hb));
  }
}

// ---------------------------------------------------------------------------
typedef __attribute__((address_space(3))) unsigned int lds_u32;
typedef const __attribute__((address_space(1))) unsigned int glb_u32;
__device__ __forceinline__ void gload16(const void* g, void* l) {
  __builtin_amdgcn_global_load_lds((glb_u32*)g, (lds_u32*)l, 16, 0, 0);
}

// raw barrier with compiler memory fences (no vmcnt drain)
__device__ __forceinline__ void syncb() {
  asm volatile("" ::: "memory");
  __builtin_amdgcn_s_barrier();
  asm volatile("" ::: "memory");
}
template<int N> __device__ __forceinline__ void wait_vmcnt() {
  if constexpr (N == 0)      asm volatile("s_waitcnt vmcnt(0)" ::: "memory");
  else if constexpr (N == 4) asm volatile("s_waitcnt vmcnt(4)" ::: "memory");
  else if constexpr (N == 7) asm volatile("s_waitcnt vmcnt(7)" ::: "memory");
}

// ---------------------------------------------------------------------------
// 8-wave counted-vmcnt split-bf16 GEMM core (T3+T4). Verified round 8.
// ---------------------------------------------------------------------------
template<int BM, int BN>
__device__ __forceinline__ void gemm_core256(
    const unsigned short* __restrict__ Ahi, const unsigned short* __restrict__ Alo,
    const unsigned short* __restrict__ Bhi, const unsigned short* __restrict__ Blo,
    int KD, f32x4 (&acc)[BM / 32][BN / 64])
{
  constexpr int MF = BM / 32, NF = BN / 64;
  constexpr int NA = BM / 64, NB = BN / 64;
  constexpr int NV = NA + NB;
  constexpr int AELT = 2 * BM * 32;
  constexpr int BELT = 2 * BN * 32;
  constexpr int ALO = BM * 32, BLO = BN * 32;
  __shared__ unsigned short lds[2][AELT + BELT];

  const int tid = threadIdx.x, lane = tid & 63, wid = tid >> 6;
  const int m0 = blockIdx.y * BM, n0 = blockIdx.x * BN;
  const int wrow = wid >> 2, wcol = wid & 3;
  const int lrow = lane & 15, g = lane >> 4;

  const unsigned short* srcA[NA]; int dstA[NA];
  #pragma unroll
  for (int i = 0; i < NA; i++) {
    int gi = tid + i * 512;
    int lr = gi >> 2, s = gi & 3, gs = s ^ ((lr >> 1) & 3);
    const unsigned short* bp = (lr < BM) ? Ahi : Alo;
    int row = (lr < BM) ? lr : lr - BM;
    srcA[i] = bp + (size_t)(m0 + row) * KD + gs * 8;
    dstA[i] = (gi & ~63) * 8;
  }
  const unsigned short* srcB[NB]; int dstB[NB];
  #pragma unroll
  for (int i = 0; i < NB; i++) {
    int gi = tid + i * 512;
    int lr = gi >> 2, s = gi & 3, gs = s ^ ((lr >> 1) & 3);
    const unsigned short* bp = (lr < BN) ? Bhi : Blo;
    int row = (lr < BN) ? lr : lr - BN;
    srcB[i] = bp + (size_t)(n0 + row) * KD + gs * 8;
    dstB[i] = AELT + (gi & ~63) * 8;
  }

  int offA[MF], offB[NF];
  #pragma unroll
  for (int m = 0; m < MF; m++) {
    int row = wrow * (BM / 2) + m * 16 + lrow;
    offA[m] = row * 32 + ((g ^ ((row >> 1) & 3)) * 8);
  }
  #pragma unroll
  for (int n = 0; n < NF; n++) {
    int row = wcol * (BN / 4) + n * 16 + lrow;
    offB[n] = AELT + row * 32 + ((g ^ ((row >> 1) & 3)) * 8);
  }

  #pragma unroll
  for (int m = 0; m < MF; m++)
    #pragma unroll
    for (int n = 0; n < NF; n++) acc[m][n] = (f32x4){0.f, 0.f, 0.f, 0.f};

  const int nk = KD / 32;

  #pragma unroll
  for (int i = 0; i < NA; i++) gload16(srcA[i], &lds[0][dstA[i]]);
  #pragma unroll
  for (int i = 0; i < NB; i++) gload16(srcB[i], &lds[0][dstB[i]]);
  #pragma unroll
  for (int i = 0; i < NA; i++) gload16(srcA[i] + 32, &lds[1][dstA[i]]);
  #pragma unroll
  for (int i = 0; i < NB; i++) gload16(srcB[i] + 32, &lds[1][dstB[i]]);
  wait_vmcnt<NV>();
  syncb();

  for (int t = 0; t < nk; ++t) {
    const unsigned short* L = lds[t & 1];

    bf16x8 bh[NF], bl[NF];
    #pragma unroll
    for (int n = 0; n < NF; n++) {
      bh[n] = *(const bf16x8*)(L + offB[n]);
      bl[n] = *(const bf16x8*)(L + offB[n] + BLO);
    }
    {
      bf16x8 ah[MF / 2], al[MF / 2];
      #pragma unroll
      for (int m = 0; m < MF / 2; m++) {
        ah[m] = *(const bf16x8*)(L + offA[m]);
        al[m] = *(const bf16x8*)(L + offA[m] + ALO);
      }
      __builtin_amdgcn_s_setprio(1);
      #pragma unroll
      for (int m = 0; m < MF / 2; m++)
        #pragma unroll
        for (int n = 0; n < NF; n++) {
          acc[m][n] = __builtin_amdgcn_mfma_f32_16x16x32_bf16(ah[m], bh[n], acc[m][n], 0, 0, 0);
          acc[m][n] = __builtin_amdgcn_mfma_f32_16x16x32_bf16(ah[m], bl[n], acc[m][n], 0, 0, 0);
          acc[m][n] = __builtin_amdgcn_mfma_f32_16x16x32_bf16(al[m], bh[n], acc[m][n], 0, 0, 0);
        }
      __builtin_amdgcn_s_setprio(0);
    }
    syncb();
    {
      bf16x8 ah[MF / 2], al[MF / 2];
      #pragma unroll
      for (int m = 0; m < MF / 2; m++) {
        ah[m] = *(const bf16x8*)(L + offA[m + MF / 2]);
        al[m] = *(const bf16x8*)(L + offA[m + MF / 2] + ALO);
      }
      __builtin_amdgcn_s_setprio(1);
      #pragma unroll
      for (int m = 0; m < MF / 2; m++)
        #pragma unroll
        for (int n = 0; n < NF; n++) {
          acc[m + MF / 2][n] = __builtin_amdgcn_mfma_f32_16x16x32_bf16(ah[m], bh[n], acc[m + MF / 2][n], 0, 0, 0);
          acc[m + MF / 2][n] = __builtin_amdgcn_mfma_f32_16x16x32_bf16(ah[m], bl[n], acc[m + MF / 2][n], 0, 0, 0);
          acc[m + MF / 2][n] = __builtin_amdgcn_mfma_f32_16x16x32_bf16(al[m], bh[n], acc[m + MF / 2][n], 0, 0, 0);
        }
      __builtin_amdgcn_s_setprio(0);
    }

    if (t + 1 < nk) {
      asm volatile("s_waitcnt lgkmcnt(0)" ::: "memory");
      syncb();
      if (t + 2 < nk) {
        const int koff = (t + 2) * 32;
        unsigned short* W = lds[t & 1];
        #pragma unroll
        for (int i = 0; i < NA; i++) gload16(srcA[i] + koff, W + dstA[i]);
        #pragma unroll
        for (int i = 0; i < NB; i++) gload16(srcB[i] + koff, W + dstB[i]);
        wait_vmcnt<NV>();
      } else {
        wait_vmcnt<0>();
      }
      syncb();
    }
  }
}

// QKV GEMM (BM=256,BN=192): scatter epilogue -> per-head split-bf16 Q/K/Vt.
__global__ __launch_bounds__(512) void gemm_qkv256(
    const unsigned short* __restrict__ Ahi, const unsigned short* __restrict__ Alo,
    const unsigned short* __restrict__ Bhi, const unsigned short* __restrict__ Blo,
    const float* __restrict__ bias,
    unsigned short* __restrict__ Qh, unsigned short* __restrict__ Ql,
    unsigned short* __restrict__ Kh, unsigned short* __restrict__ Kl,
    unsigned short* __restrict__ Vth, unsigned short* __restrict__ Vtl)
{
  f32x4 acc[8][3];
  gemm_core256<256, 192>(Ahi, Alo, Bhi, Blo, 1024, acc);

  const int tid = threadIdx.x, lane = tid & 63, wid = tid >> 6;
  const int lrow = lane & 15, g = lane >> 4;
  const int m0 = blockIdx.y * 256, n0 = blockIdx.x * 192;
  const int wrow = wid >> 2, wcol = wid & 3;
  const int bidx = m0 >> 11;
  const int sbase = (m0 & 2047) + wrow * 128 + g * 4;
  #pragma unroll
  for (int n = 0; n < 3; n++) {
    int gcol = n0 + wcol * 48 + n * 16 + lrow;
    unsigned hh = (unsigned)gcol / 192u;
    int inner = gcol - (int)hh * 192;
    int part = inner >> 6;
    int d = inner & 63;
    float bv = bias[gcol];
    size_t base = (size_t)(bidx * 16 + (int)hh) * 131072;
    #pragma unroll
    for (int m = 0; m < 8; m++) {
      f32x4 a = acc[m][n];
      int s0 = sbase + m * 16;
      if (part == 0) {
        #pragma unroll
        for (int r = 0; r < 4; r++) {
          float v = (a[r] + bv) * 0.18033688011112042f;  // 0.125 * log2(e)
          unsigned short hi = bf16_rn(v);
          size_t ix = base + (size_t)(s0 + r) * 64 + d;
          Qh[ix] = hi; Ql[ix] = bf16_rn(v - bf16_f(hi));
        }
      } else if (part == 1) {
        #pragma unroll
        for (int r = 0; r < 4; r++) {
          float v = a[r] + bv;
          unsigned short hi = bf16_rn(v);
          size_t ix = base + (size_t)(s0 + r) * 64 + d;
          Kh[ix] = hi; Kl[ix] = bf16_rn(v - bf16_f(hi));
        }
      } else {
        u16x4 hv, lv;
        #pragma unroll
        for (int r = 0; r < 4; r++) {
          float v = a[r] + bv;
          hv[r] = bf16_rn(v);
          lv[r] = bf16_rn(v - bf16_f(hv[r]));
        }
        size_t ix = base + (size_t)d * 2048 + s0;
        *(u16x4*)(Vth + ix) = hv;
        *(u16x4*)(Vtl + ix) = lv;
      }
    }
  }
}

// Out-projection GEMM (BM=BN=128): plain f32 + bias epilogue.
__global__ __launch_bounds__(512) void gemm_out256(
    const unsigned short* __restrict__ Ahi, const unsigned short* __restrict__ Alo,
    const unsigned short* __restrict__ Bhi, const unsigned short* __restrict__ Blo,
    const float* __restrict__ bias, float* __restrict__ C)
{
  f32x4 acc[4][2];
  gemm_core256<128, 128>(Ahi, Alo, Bhi, Blo, 1024, acc);

  const int tid = threadIdx.x, lane = tid & 63, wid = tid >> 6;
  const int lrow = lane & 15, g = lane >> 4;
  const int m0 = blockIdx.y * 128, n0 = blockIdx.x * 128;
  const int wrow = wid >> 2, wcol = wid & 3;
  #pragma unroll
  for (int n = 0; n < 2; n++) {
    int gcol = n0 + wcol * 32 + n * 16 + lrow;
    float bv = bias[gcol];
    #pragma unroll
    for (int m = 0; m < 4; m++) {
      f32x4 a = acc[m][n];
      #pragma unroll
      for (int r = 0; r < 4; r++) {
        int grow = m0 + wrow * 64 + m * 16 + g * 4 + r;
        C[(size_t)grow * 1024 + gcol] = a[r] + bv;
      }
    }
  }
}

// ---------------------------------------------------------------------------
// MFMA flash attention v3: causal-balanced pairing (8 waves x 32 rows),
// K LDS-staged (2-phase dbuf), V read DIRECT from global (L2-hot, 8-wave
// reuse; un-staging per m169), row-sum via ones-MFMA into lacc (replaces
// 32 shfl+add/tile), exp2-domain softmax. LDS 64KB -> 2 blocks/CU.
// ---------------------------------------------------------------------------
__global__ __launch_bounds__(512, 4) void flash_attn_mfma(
    const unsigned short* __restrict__ Qh, const unsigned short* __restrict__ Ql,
    const unsigned short* __restrict__ Kh, const unsigned short* __restrict__ Kl,
    const unsigned short* __restrict__ Vth, const unsigned short* __restrict__ Vtl,
    unsigned short* __restrict__ atthi, unsigned short* __restrict__ attlo)
{
  const int pidx = blockIdx.x;
  const int h = blockIdx.y, b = blockIdx.z;
  const int bh = b * Hh + h;
  const int NT = Ss / 128;
  const int qtA = pidx, qtB = NT - 1 - pidx;
  const int tid = threadIdx.x, lane = tid & 63, wid = tid >> 6;
  const int q0w = (wid < 4) ? (qtA * 128 + wid * 32)
                            : (qtB * 128 + (wid - 4) * 32);
  const int lrow = lane & 15, lg = lane >> 4;

  __shared__ unsigned short KH[2][4096], KL[2][4096];   // 32 KB
  __shared__ unsigned short Pbuf[8][2048];              // 32 KB

  const size_t hb = (size_t)bh * 131072;
  const unsigned short* qhb = Qh + hb;
  const unsigned short* qlb = Ql + hb;
  const unsigned short* khb = Kh + hb;
  const unsigned short* klb = Kl + hb;
  const unsigned short* vhb = Vth + hb;
  const unsigned short* vlb = Vtl + hb;

  // Q fragments in registers (pre-scaled by log2e/8 in GEMM epilogue)
  bf16x8 qfh[2][2], qfl[2][2];
  #pragma unroll
  for (int mi = 0; mi < 2; mi++)
    #pragma unroll
    for (int ks = 0; ks < 2; ks++) {
      int off = (q0w + mi * 16 + lrow) * 64 + ks * 32 + lg * 8;
      qfh[mi][ks] = *(const bf16x8*)(qhb + off);
      qfl[mi][ks] = *(const bf16x8*)(qlb + off);
    }

  // ones B-fragment for the row-sum MFMA (bf16 1.0 = 0x3F80)
  bf16x8 onesf;
  #pragma unroll
  for (int j = 0; j < 8; j++) onesf[j] = (short)0x3F80;

  // K LDS fragment offsets (swizzle g^(row&7)); P offsets same pattern
  int offK[4][2], offP[2][2];
  #pragma unroll
  for (int ci = 0; ci < 4; ci++)
    #pragma unroll
    for (int ks = 0; ks < 2; ks++) {
      int row = ci * 16 + lrow;
      offK[ci][ks] = row * 64 + (((ks * 4 + lg) ^ (row & 7)) * 8);
    }
  #pragma unroll
  for (int mi = 0; mi < 2; mi++)
    #pragma unroll
    for (int ks = 0; ks < 2; ks++) {
      int row = mi * 16 + lrow;
      offP[mi][ks] = row * 64 + (((ks * 4 + lg) ^ (row & 7)) * 8);
    }

  // V^T direct-global per-lane base: row = di*16+lrow (d-dim), col = kv+ks*32+lg*8
  const unsigned short* vhrow = vhb + (size_t)lrow * 2048 + lg * 8;
  const unsigned short* vlrow = vlb + (size_t)lrow * 2048 + lg * 8;

  // K staging: 512 threads x 1 granule per array per tile
  const int sr = tid >> 3, sg = ((tid & 7) ^ ((tid >> 3) & 7)) * 8;

  float m_[2][4];
  f32x4 lacc[2];          // row-sum accumulator (ones-MFMA), rescaled by alpha
  f32x4 oacc[2][4];
  #pragma unroll
  for (int mi = 0; mi < 2; mi++) {
    lacc[mi] = (f32x4){0.f, 0.f, 0.f, 0.f};
    #pragma unroll
    for (int r = 0; r < 4; r++) m_[mi][r] = -INFINITY;
    #pragma unroll
    for (int di = 0; di < 4; di++) oacc[mi][di] = (f32x4){0.f, 0.f, 0.f, 0.f};
  }

  unsigned short* Pw = Pbuf[wid];
  const int nt = 2 * (qtB + 1);

  // prologue: stage K tile 0
  gload16(khb + (size_t)sr * 64 + sg, KH[0] + wid * 512);
  gload16(klb + (size_t)sr * 64 + sg, KL[0] + wid * 512);
  __syncthreads();

  for (int t = 0; t < nt; ++t) {
    const int kv0 = t * 64;
    // prefetch next K tile (overlaps compute; end-of-tile barrier drains)
    if (t + 1 < nt) {
      const int nb = (t + 1) & 1;
      const int nk = kv0 + 64;
      gload16(khb + (size_t)(nk + sr) * 64 + sg, KH[nb] + wid * 512);
      gload16(klb + (size_t)(nk + sr) * 64 + sg, KL[nb] + wid * 512);
    }

    if (kv0 <= q0w + 31) {
      const int cb = t & 1;
      const unsigned short* KHc = KH[cb];
      const unsigned short* KLc = KL[cb];

      // S = Q K^T (3-term split)
      f32x4 sf[2][4];
      #pragma unroll
      for (int mi = 0; mi < 2; mi++)
        #pragma unroll
        for (int ci = 0; ci < 4; ci++) sf[mi][ci] = (f32x4){0.f, 0.f, 0.f, 0.f};
      __builtin_amdgcn_s_setprio(1);
      #pragma unroll
      for (int ci = 0; ci < 4; ci++) {
        bf16x8 kh0 = *(const bf16x8*)(KHc + offK[ci][0]);
        bf16x8 kh1 = *(const bf16x8*)(KHc + offK[ci][1]);
        bf16x8 kl0 = *(const bf16x8*)(KLc + offK[ci][0]);
        bf16x8 kl1 = *(const bf16x8*)(KLc + offK[ci][1]);
        #pragma unroll
        for (int mi = 0; mi < 2; mi++) {
          f32x4 s = sf[mi][ci];
          s = __builtin_amdgcn_mfma_f32_16x16x32_bf16(qfh[mi][0], kh0, s, 0, 0, 0);
          s = __builtin_amdgcn_mfma_f32_16x16x32_bf16(qfh[mi][1], kh1, s, 0, 0, 0);
          s = __builtin_amdgcn_mfma_f32_16x16x32_bf16(qfh[mi][0], kl0, s, 0, 0, 0);
          s = __builtin_amdgcn_mfma_f32_16x16x32_bf16(qfh[mi][1], kl1, s, 0, 0, 0);
          s = __builtin_amdgcn_mfma_f32_16x16x32_bf16(qfl[mi][0], kh0, s, 0, 0, 0);
          s = __builtin_amdgcn_mfma_f32_16x16x32_bf16(qfl[mi][1], kh1, s, 0, 0, 0);
          sf[mi][ci] = s;
        }
      }
      __builtin_amdgcn_s_setprio(0);

      // causal mask on straddling tiles
      if (kv0 + 63 > q0w) {
        #pragma unroll
        for (int mi = 0; mi < 2; mi++)
          #pragma unroll
          for (int ci = 0; ci < 4; ci++)
            #pragma unroll
            for (int r = 0; r < 4; r++) {
              int q = q0w + mi * 16 + lg * 4 + r;
              int kv = kv0 + ci * 16 + lrow;
              if (kv > q) sf[mi][ci][r] = -1e30f;
            }
      }

      // online softmax (log2 domain). Sum-reduce removed: done via ones-MFMA.
      #pragma unroll
      for (int mi = 0; mi < 2; mi++)
        #pragma unroll
        for (int r = 0; r < 4; r++) {
          float mx = fmaxf(fmaxf(sf[mi][0][r], sf[mi][1][r]),
                           fmaxf(sf[mi][2][r], sf[mi][3][r]));
          mx = fmaxf(mx, __shfl_xor(mx, 1));
          mx = fmaxf(mx, __shfl_xor(mx, 2));
          mx = fmaxf(mx, __shfl_xor(mx, 4));
          mx = fmaxf(mx, __shfl_xor(mx, 8));
          float mn = fmaxf(m_[mi][r], mx);
          float alpha = __builtin_amdgcn_exp2f(m_[mi][r] - mn);
          m_[mi][r] = mn;
          #pragma unroll
          for (int ci = 0; ci < 4; ci++)
            sf[mi][ci][r] = __builtin_amdgcn_exp2f(sf[mi][ci][r] - mn);
          lacc[mi][r] *= alpha;
          #pragma unroll
          for (int di = 0; di < 4; di++) oacc[mi][di][r] *= alpha;
        }

      // P -> wave-private LDS as bf16 (swizzled)
      #pragma unroll
      for (int mi = 0; mi < 2; mi++)
        #pragma unroll
        for (int ci = 0; ci < 4; ci++) {
          int colb = ci * 16 + lrow;
          int gcol = colb >> 3, crem = colb & 7;
          #pragma unroll
          for (int r = 0; r < 4; r++) {
            int rr = mi * 16 + lg * 4 + r;
            Pw[rr * 64 + ((gcol ^ (rr & 7)) * 8) + crem] = bf16_rn(sf[mi][ci][r]);
          }
        }

      bf16x8 pa[2][2];
      #pragma unroll
      for (int mi = 0; mi < 2; mi++)
        #pragma unroll
        for (int ks = 0; ks < 2; ks++)
          pa[mi][ks] = *(const bf16x8*)(Pw + offP[mi][ks]);

      // l += P · 1 (row sums via MFMA; replaces shfl sum-reduce)
      #pragma unroll
      for (int mi = 0; mi < 2; mi++) {
        lacc[mi] = __builtin_amdgcn_mfma_f32_16x16x32_bf16(pa[mi][0], onesf, lacc[mi], 0, 0, 0);
        lacc[mi] = __builtin_amdgcn_mfma_f32_16x16x32_bf16(pa[mi][1], onesf, lacc[mi], 0, 0, 0);
      }

      // O += P (Vh + Vl); V^T fragments direct from global (per-di batches)
      __builtin_amdgcn_s_setprio(1);
      #pragma unroll
      for (int di = 0; di < 4; di++) {
        const unsigned short* vh = vhrow + (size_t)(di * 16) * 2048 + kv0;
        const unsigned short* vl = vlrow + (size_t)(di * 16) * 2048 + kv0;
        bf16x8 vh0 = *(const bf16x8*)(vh);
        bf16x8 vh1 = *(const bf16x8*)(vh + 32);
        bf16x8 vl0 = *(const bf16x8*)(vl);
        bf16x8 vl1 = *(const bf16x8*)(vl + 32);
        #pragma unroll
        for (int mi = 0; mi < 2; mi++) {
          f32x4 o = oacc[mi][di];
          o = __builtin_amdgcn_mfma_f32_16x16x32_bf16(pa[mi][0], vh0, o, 0, 0, 0);
          o = __builtin_amdgcn_mfma_f32_16x16x32_bf16(pa[mi][1], vh1, o, 0, 0, 0);
          o = __builtin_amdgcn_mfma_f32_16x16x32_bf16(pa[mi][0], vl0, o, 0, 0, 0);
          o = __builtin_amdgcn_mfma_f32_16x16x32_bf16(pa[mi][1], vl1, o, 0, 0, 0);
          oacc[mi][di] = o;
        }
      }
      __builtin_amdgcn_s_setprio(0);
    }
    __syncthreads();   // drains vmcnt: next K buffer ready; cur reusable
  }

  // epilogue: normalize by lacc, write split-bf16 att [B*S][1024]
  #pragma unroll
  for (int mi = 0; mi < 2; mi++) {
    float inv[4];
    #pragma unroll
    for (int r = 0; r < 4; r++) inv[r] = 1.f / lacc[mi][r];
    #pragma unroll
    for (int di = 0; di < 4; di++) {
      f32x4 o = oacc[mi][di];
      #pragma unroll
      for (int r = 0; r < 4; r++) {
        float v = o[r] * inv[r];
        int srow = q0w + mi * 16 + lg * 4 + r;
        size_t idx = ((size_t)b * Ss + srow) * 1024 + h * 64 + di * 16 + lrow;
        unsigned short hi = bf16_rn(v);
        atthi[idx] = hi;
        attlo[idx] = bf16_rn(v - bf16_f(hi));
      }
    }
  }
}

// ---------------------------------------------------------------------------
extern "C" void kernel_launch(void* const* d_in, const int* in_sizes, int n_in,
                              void* d_out, int out_size, void* d_ws, size_t ws_size,
                              hipStream_t stream) {
  const float* x    = (const float*)d_in[0];
  // d_in[1] = causal mask (hardcoded)
  const float* Wqkv = (const float*)d_in[2];
  const float* bqkv = (const float*)d_in[3];
  const float* Wout = (const float*)d_in[4];
  const float* bout = (const float*)d_in[5];
  float* out = (float*)d_out;

  char* ws = (char*)d_ws;
  unsigned short* Qh  = (unsigned short*)(ws);
  unsigned short* Ql  = (unsigned short*)(ws + 8388608);
  unsigned short* Kh  = (unsigned short*)(ws + 16777216);
  unsigned short* Kl  = (unsigned short*)(ws + 25165824);
  unsigned short* Vth = (unsigned short*)(ws + 33554432);
  unsigned short* Vtl = (unsigned short*)(ws + 41943040);
  unsigned short* atthi = (unsigned short*)(ws + 50331648);
  unsigned short* attlo = (unsigned short*)(ws + 58720256);
  unsigned short* xhi = (unsigned short*)(ws + 67108864);
  unsigned short* xlo = (unsigned short*)(ws + 75497472);
  unsigned short* wqh = (unsigned short*)(ws + 83886080);
  unsigned short* wql = (unsigned short*)(ws + 90177536);
  unsigned short* woh = (unsigned short*)(ws + 96468992);
  unsigned short* wol = (unsigned short*)(ws + 98566144);

  const int M = Bb * Ss;  // 4096

  split_f32<<<(M * Dd / 8) / 256, 256, 0, stream>>>(x, xhi, xlo, M * Dd / 8);
  transpose_split_f32<<<dim3(3 * Dd / 32, Dd / 32), 256, 0, stream>>>(Wqkv, wqh, wql, Dd, 3 * Dd);
  transpose_split_f32<<<dim3(Dd / 32, Dd / 32), 256, 0, stream>>>(Wout, woh, wol, Dd, Dd);

  // 1) QKV projection: 256x192 tile, counted-vmcnt pipeline, scatter epilogue
  gemm_qkv256<<<dim3(16, 16), 512, 0, stream>>>(
      xhi, xlo, wqh, wql, bqkv, Qh, Ql, Kh, Kl, Vth, Vtl);

  // 2) MFMA causal flash attention (pairing + direct-global V + ones-MFMA sum)
  flash_attn_mfma<<<dim3(Ss / 256, Hh, Bb), 512, 0, stream>>>(
      Qh, Ql, Kh, Kl, Vth, Vtl, atthi, attlo);

  // 3) output projection: 128x128 tile, 8 waves, counted-vmcnt pipeline
  gemm_out256<<<dim3(8, 32), 512, 0, stream>>>(
      atthi, attlo, woh, wol, bout, out);
}

// Round 12
// 312.728 us; speedup vs baseline: 2.1330x; 2.1330x over previous
//
#include <hip/hip_runtime.h>
#include <math.h>

// Problem constants
constexpr int Bb = 2, Ss = 2048, Dd = 1024, Hh = 16, HDd = 64;

typedef __attribute__((ext_vector_type(8))) short bf16x8;     // MFMA A/B frag
typedef __attribute__((ext_vector_type(4))) float f32x4;      // MFMA C/D frag
typedef __attribute__((ext_vector_type(8))) unsigned short u16x8;
typedef __attribute__((ext_vector_type(4))) unsigned short u16x4;

__device__ __forceinline__ unsigned short bf16_rn(float f) {
  unsigned int u = __float_as_uint(f);
  u += 0x7fffu + ((u >> 16) & 1u);
  return (unsigned short)(u >> 16);
}
__device__ __forceinline__ float bf16_f(unsigned short h) {
  return __uint_as_float(((unsigned int)h) << 16);
}

// ---------------------------------------------------------------------------
// split fp32 array into hi/lo bf16 arrays
// ---------------------------------------------------------------------------
__global__ __launch_bounds__(256) void split_f32(
    const float* __restrict__ in, unsigned short* __restrict__ hi,
    unsigned short* __restrict__ lo, int n8) {
  int i = blockIdx.x * 256 + threadIdx.x;
  if (i >= n8) return;
  const float4* p = (const float4*)in + (size_t)i * 2;
  float4 a = p[0], b = p[1];
  float v[8] = {a.x, a.y, a.z, a.w, b.x, b.y, b.z, b.w};
  u16x8 h, l;
  #pragma unroll
  for (int j = 0; j < 8; j++) {
    unsigned short hb = bf16_rn(v[j]);
    h[j] = hb;
    l[j] = bf16_rn(v[j] - bf16_f(hb));
  }
  *(u16x8*)(hi + (size_t)i * 8) = h;
  *(u16x8*)(lo + (size_t)i * 8) = l;
}

// transpose W[K][N] -> Wt[N][K], split into hi/lo bf16
__global__ __launch_bounds__(256) void transpose_split_f32(
    const float* __restrict__ W, unsigned short* __restrict__ Thi,
    unsigned short* __restrict__ Tlo, int K, int N) {
  __shared__ float tile[32][33];
  int n0 = blockIdx.x * 32, k0 = blockIdx.y * 32;
  int t = threadIdx.x;
  #pragma unroll
  for (int p = 0; p < 4; p++) {
    int idx = t + p * 256;
    int kk = idx >> 5, nn = idx & 31;
    tile[kk][nn] = W[(size_t)(k0 + kk) * N + n0 + nn];
  }
  __syncthreads();
  #pragma unroll
  for (int p = 0; p < 4; p++) {
    int idx = t + p * 256;
    int nn = idx >> 5, kk = idx & 31;
    float v = tile[kk][nn];
    unsigned short hb = bf16_rn(v);
    size_t o = (size_t)(n0 + nn) * K + k0 + kk;
    Thi[o] = hb;
    Tlo[o] = bf16_rn(v - bf16_f(hb));
  }
}

// ---------------------------------------------------------------------------
typedef __attribute__((address_space(3))) unsigned int lds_u32;
typedef const __attribute__((address_space(1))) unsigned int glb_u32;
__device__ __forceinline__ void gload16(const void* g, void* l) {
  __builtin_amdgcn_global_load_lds((glb_u32*)g, (lds_u32*)l, 16, 0, 0);
}

// raw barrier with compiler memory fences (no vmcnt drain)
__device__ __forceinline__ void syncb() {
  asm volatile("" ::: "memory");
  __builtin_amdgcn_s_barrier();
  asm volatile("" ::: "memory");
}
template<int N> __device__ __forceinline__ void wait_vmcnt() {
  if constexpr (N == 0)      asm volatile("s_waitcnt vmcnt(0)" ::: "memory");
  else if constexpr (N == 2) asm volatile("s_waitcnt vmcnt(2)" ::: "memory");
  else if constexpr (N == 4) asm volatile("s_waitcnt vmcnt(4)" ::: "memory");
  else if constexpr (N == 7) asm volatile("s_waitcnt vmcnt(7)" ::: "memory");
}

// ---------------------------------------------------------------------------
// 8-wave counted-vmcnt split-bf16 GEMM core (T3+T4). Verified round 8.
// ---------------------------------------------------------------------------
template<int BM, int BN>
__device__ __forceinline__ void gemm_core256(
    const unsigned short* __restrict__ Ahi, const unsigned short* __restrict__ Alo,
    const unsigned short* __restrict__ Bhi, const unsigned short* __restrict__ Blo,
    int KD, f32x4 (&acc)[BM / 32][BN / 64])
{
  constexpr int MF = BM / 32, NF = BN / 64;
  constexpr int NA = BM / 64, NB = BN / 64;
  constexpr int NV = NA + NB;
  constexpr int AELT = 2 * BM * 32;
  constexpr int BELT = 2 * BN * 32;
  constexpr int ALO = BM * 32, BLO = BN * 32;
  __shared__ unsigned short lds[2][AELT + BELT];

  const int tid = threadIdx.x, lane = tid & 63, wid = tid >> 6;
  const int m0 = blockIdx.y * BM, n0 = blockIdx.x * BN;
  const int wrow = wid >> 2, wcol = wid & 3;
  const int lrow = lane & 15, g = lane >> 4;

  const unsigned short* srcA[NA]; int dstA[NA];
  #pragma unroll
  for (int i = 0; i < NA; i++) {
    int gi = tid + i * 512;
    int lr = gi >> 2, s = gi & 3, gs = s ^ ((lr >> 1) & 3);
    const unsigned short* bp = (lr < BM) ? Ahi : Alo;
    int row = (lr < BM) ? lr : lr - BM;
    srcA[i] = bp + (size_t)(m0 + row) * KD + gs * 8;
    dstA[i] = (gi & ~63) * 8;
  }
  const unsigned short* srcB[NB]; int dstB[NB];
  #pragma unroll
  for (int i = 0; i < NB; i++) {
    int gi = tid + i * 512;
    int lr = gi >> 2, s = gi & 3, gs = s ^ ((lr >> 1) & 3);
    const unsigned short* bp = (lr < BN) ? Bhi : Blo;
    int row = (lr < BN) ? lr : lr - BN;
    srcB[i] = bp + (size_t)(n0 + row) * KD + gs * 8;
    dstB[i] = AELT + (gi & ~63) * 8;
  }

  int offA[MF], offB[NF];
  #pragma unroll
  for (int m = 0; m < MF; m++) {
    int row = wrow * (BM / 2) + m * 16 + lrow;
    offA[m] = row * 32 + ((g ^ ((row >> 1) & 3)) * 8);
  }
  #pragma unroll
  for (int n = 0; n < NF; n++) {
    int row = wcol * (BN / 4) + n * 16 + lrow;
    offB[n] = AELT + row * 32 + ((g ^ ((row >> 1) & 3)) * 8);
  }

  #pragma unroll
  for (int m = 0; m < MF; m++)
    #pragma unroll
    for (int n = 0; n < NF; n++) acc[m][n] = (f32x4){0.f, 0.f, 0.f, 0.f};

  const int nk = KD / 32;

  #pragma unroll
  for (int i = 0; i < NA; i++) gload16(srcA[i], &lds[0][dstA[i]]);
  #pragma unroll
  for (int i = 0; i < NB; i++) gload16(srcB[i], &lds[0][dstB[i]]);
  #pragma unroll
  for (int i = 0; i < NA; i++) gload16(srcA[i] + 32, &lds[1][dstA[i]]);
  #pragma unroll
  for (int i = 0; i < NB; i++) gload16(srcB[i] + 32, &lds[1][dstB[i]]);
  wait_vmcnt<NV>();
  syncb();

  for (int t = 0; t < nk; ++t) {
    const unsigned short* L = lds[t & 1];

    bf16x8 bh[NF], bl[NF];
    #pragma unroll
    for (int n = 0; n < NF; n++) {
      bh[n] = *(const bf16x8*)(L + offB[n]);
      bl[n] = *(const bf16x8*)(L + offB[n] + BLO);
    }
    {
      bf16x8 ah[MF / 2], al[MF / 2];
      #pragma unroll
      for (int m = 0; m < MF / 2; m++) {
        ah[m] = *(const bf16x8*)(L + offA[m]);
        al[m] = *(const bf16x8*)(L + offA[m] + ALO);
      }
      __builtin_amdgcn_s_setprio(1);
      #pragma unroll
      for (int m = 0; m < MF / 2; m++)
        #pragma unroll
        for (int n = 0; n < NF; n++) {
          acc[m][n] = __builtin_amdgcn_mfma_f32_16x16x32_bf16(ah[m], bh[n], acc[m][n], 0, 0, 0);
          acc[m][n] = __builtin_amdgcn_mfma_f32_16x16x32_bf16(ah[m], bl[n], acc[m][n], 0, 0, 0);
          acc[m][n] = __builtin_amdgcn_mfma_f32_16x16x32_bf16(al[m], bh[n], acc[m][n], 0, 0, 0);
        }
      __builtin_amdgcn_s_setprio(0);
    }
    syncb();
    {
      bf16x8 ah[MF / 2], al[MF / 2];
      #pragma unroll
      for (int m = 0; m < MF / 2; m++) {
        ah[m] = *(const bf16x8*)(L + offA[m + MF / 2]);
        al[m] = *(const bf16x8*)(L + offA[m + MF / 2] + ALO);
      }
      __builtin_amdgcn_s_setprio(1);
      #pragma unroll
      for (int m = 0; m < MF / 2; m++)
        #pragma unroll
        for (int n = 0; n < NF; n++) {
          acc[m + MF / 2][n] = __builtin_amdgcn_mfma_f32_16x16x32_bf16(ah[m], bh[n], acc[m + MF / 2][n], 0, 0, 0);
          acc[m + MF / 2][n] = __builtin_amdgcn_mfma_f32_16x16x32_bf16(ah[m], bl[n], acc[m + MF / 2][n], 0, 0, 0);
          acc[m + MF / 2][n] = __builtin_amdgcn_mfma_f32_16x16x32_bf16(al[m], bh[n], acc[m + MF / 2][n], 0, 0, 0);
        }
      __builtin_amdgcn_s_setprio(0);
    }

    if (t + 1 < nk) {
      asm volatile("s_waitcnt lgkmcnt(0)" ::: "memory");
      syncb();
      if (t + 2 < nk) {
        const int koff = (t + 2) * 32;
        unsigned short* W = lds[t & 1];
        #pragma unroll
        for (int i = 0; i < NA; i++) gload16(srcA[i] + koff, W + dstA[i]);
        #pragma unroll
        for (int i = 0; i < NB; i++) gload16(srcB[i] + koff, W + dstB[i]);
        wait_vmcnt<NV>();
      } else {
        wait_vmcnt<0>();
      }
      syncb();
    }
  }
}

// QKV GEMM (BM=256,BN=192): scatter epilogue -> per-head split-bf16 Q/K/Vt.
__global__ __launch_bounds__(512) void gemm_qkv256(
    const unsigned short* __restrict__ Ahi, const unsigned short* __restrict__ Alo,
    const unsigned short* __restrict__ Bhi, const unsigned short* __restrict__ Blo,
    const float* __restrict__ bias,
    unsigned short* __restrict__ Qh, unsigned short* __restrict__ Ql,
    unsigned short* __restrict__ Kh, unsigned short* __restrict__ Kl,
    unsigned short* __restrict__ Vth, unsigned short* __restrict__ Vtl)
{
  f32x4 acc[8][3];
  gemm_core256<256, 192>(Ahi, Alo, Bhi, Blo, 1024, acc);

  const int tid = threadIdx.x, lane = tid & 63, wid = tid >> 6;
  const int lrow = lane & 15, g = lane >> 4;
  const int m0 = blockIdx.y * 256, n0 = blockIdx.x * 192;
  const int wrow = wid >> 2, wcol = wid & 3;
  const int bidx = m0 >> 11;
  const int sbase = (m0 & 2047) + wrow * 128 + g * 4;
  #pragma unroll
  for (int n = 0; n < 3; n++) {
    int gcol = n0 + wcol * 48 + n * 16 + lrow;
    unsigned hh = (unsigned)gcol / 192u;
    int inner = gcol - (int)hh * 192;
    int part = inner >> 6;
    int d = inner & 63;
    float bv = bias[gcol];
    size_t base = (size_t)(bidx * 16 + (int)hh) * 131072;
    #pragma unroll
    for (int m = 0; m < 8; m++) {
      f32x4 a = acc[m][n];
      int s0 = sbase + m * 16;
      if (part == 0) {
        #pragma unroll
        for (int r = 0; r < 4; r++) {
          float v = (a[r] + bv) * 0.18033688011112042f;  // 0.125 * log2(e)
          unsigned short hi = bf16_rn(v);
          size_t ix = base + (size_t)(s0 + r) * 64 + d;
          Qh[ix] = hi; Ql[ix] = bf16_rn(v - bf16_f(hi));
        }
      } else if (part == 1) {
        #pragma unroll
        for (int r = 0; r < 4; r++) {
          float v = a[r] + bv;
          unsigned short hi = bf16_rn(v);
          size_t ix = base + (size_t)(s0 + r) * 64 + d;
          Kh[ix] = hi; Kl[ix] = bf16_rn(v - bf16_f(hi));
        }
      } else {
        u16x4 hv, lv;
        #pragma unroll
        for (int r = 0; r < 4; r++) {
          float v = a[r] + bv;
          hv[r] = bf16_rn(v);
          lv[r] = bf16_rn(v - bf16_f(hv[r]));
        }
        size_t ix = base + (size_t)d * 2048 + s0;
        *(u16x4*)(Vth + ix) = hv;
        *(u16x4*)(Vtl + ix) = lv;
      }
    }
  }
}

// Out-projection GEMM (BM=BN=128): plain f32 + bias epilogue.
__global__ __launch_bounds__(512) void gemm_out256(
    const unsigned short* __restrict__ Ahi, const unsigned short* __restrict__ Alo,
    const unsigned short* __restrict__ Bhi, const unsigned short* __restrict__ Blo,
    const float* __restrict__ bias, float* __restrict__ C)
{
  f32x4 acc[4][2];
  gemm_core256<128, 128>(Ahi, Alo, Bhi, Blo, 1024, acc);

  const int tid = threadIdx.x, lane = tid & 63, wid = tid >> 6;
  const int lrow = lane & 15, g = lane >> 4;
  const int m0 = blockIdx.y * 128, n0 = blockIdx.x * 128;
  const int wrow = wid >> 2, wcol = wid & 3;
  #pragma unroll
  for (int n = 0; n < 2; n++) {
    int gcol = n0 + wcol * 32 + n * 16 + lrow;
    float bv = bias[gcol];
    #pragma unroll
    for (int m = 0; m < 4; m++) {
      f32x4 a = acc[m][n];
      #pragma unroll
      for (int r = 0; r < 4; r++) {
        int grow = m0 + wrow * 64 + m * 16 + g * 4 + r;
        C[(size_t)grow * 1024 + gcol] = a[r] + bv;
      }
    }
  }
}

// ---------------------------------------------------------------------------
// MFMA flash attention v4 (round-8 structure + LDS diet):
// causal-balanced pairing, 8 waves x 32 rows. K double-buffered in LDS;
// V SINGLE-buffered (PV consumes V late -> load hides under QK^T+softmax).
// LDS = 80KB -> 2 blocks/CU without any register cap (round-9 lesson:
// __launch_bounds__ min-waves forced a spill catastrophe). Counted vmcnt:
// issue V(t),K(t+1) -> vmcnt(4) [K(t) resident] -> barrier -> QK^T/softmax/P
// -> vmcnt(2) [V(t) resident] -> barrier -> PV -> barrier.
// ---------------------------------------------------------------------------
__global__ __launch_bounds__(512) void flash_attn_mfma(
    const unsigned short* __restrict__ Qh, const unsigned short* __restrict__ Ql,
    const unsigned short* __restrict__ Kh, const unsigned short* __restrict__ Kl,
    const unsigned short* __restrict__ Vth, const unsigned short* __restrict__ Vtl,
    unsigned short* __restrict__ atthi, unsigned short* __restrict__ attlo)
{
  const int pidx = blockIdx.x;
  const int h = blockIdx.y, b = blockIdx.z;
  const int bh = b * Hh + h;
  const int NT = Ss / 128;
  const int qtA = pidx, qtB = NT - 1 - pidx;
  const int tid = threadIdx.x, lane = tid & 63, wid = tid >> 6;
  const int q0w = (wid < 4) ? (qtA * 128 + wid * 32)
                            : (qtB * 128 + (wid - 4) * 32);
  const int lrow = lane & 15, lg = lane >> 4;

  __shared__ unsigned short KH[2][4096], KL[2][4096];   // 32 KB (K dbuf)
  __shared__ unsigned short VH[4096], VL[4096];         // 16 KB (V single)
  __shared__ unsigned short Pbuf[8][2048];              // 32 KB

  const size_t hb = (size_t)bh * 131072;
  const unsigned short* qhb = Qh + hb;
  const unsigned short* qlb = Ql + hb;
  const unsigned short* khb = Kh + hb;
  const unsigned short* klb = Kl + hb;
  const unsigned short* vhb = Vth + hb;
  const unsigned short* vlb = Vtl + hb;

  // Q fragments in registers (pre-scaled by log2e/8 in GEMM epilogue)
  bf16x8 qfh[2][2], qfl[2][2];
  #pragma unroll
  for (int mi = 0; mi < 2; mi++)
    #pragma unroll
    for (int ks = 0; ks < 2; ks++) {
      int off = (q0w + mi * 16 + lrow) * 64 + ks * 32 + lg * 8;
      qfh[mi][ks] = *(const bf16x8*)(qhb + off);
      qfl[mi][ks] = *(const bf16x8*)(qlb + off);
    }

  // LDS fragment offsets (swizzle g^(row&7)); K/V/P all same pattern
  int offK[4][2], offP[2][2];
  #pragma unroll
  for (int ci = 0; ci < 4; ci++)
    #pragma unroll
    for (int ks = 0; ks < 2; ks++) {
      int row = ci * 16 + lrow;
      offK[ci][ks] = row * 64 + (((ks * 4 + lg) ^ (row & 7)) * 8);
    }
  #pragma unroll
  for (int mi = 0; mi < 2; mi++)
    #pragma unroll
    for (int ks = 0; ks < 2; ks++) {
      int row = mi * 16 + lrow;
      offP[mi][ks] = row * 64 + (((ks * 4 + lg) ^ (row & 7)) * 8);
    }

  // staging: 512 threads x 1 granule per array per tile
  const int sr = tid >> 3, sg = ((tid & 7) ^ ((tid >> 3) & 7)) * 8;

  float m_[2][4], l_[2][4];
  f32x4 oacc[2][4];
  #pragma unroll
  for (int mi = 0; mi < 2; mi++)
    #pragma unroll
    for (int r = 0; r < 4; r++) { m_[mi][r] = -INFINITY; l_[mi][r] = 0.f; }
  #pragma unroll
  for (int mi = 0; mi < 2; mi++)
    #pragma unroll
    for (int di = 0; di < 4; di++) oacc[mi][di] = (f32x4){0.f, 0.f, 0.f, 0.f};

  unsigned short* Pw = Pbuf[wid];
  const int nt = 2 * (qtB + 1);

  // prologue: issue K(0) (V(0) issued at top of t=0)
  gload16(khb + (size_t)sr * 64 + sg, KH[0] + wid * 512);
  gload16(klb + (size_t)sr * 64 + sg, KL[0] + wid * 512);

  for (int t = 0; t < nt; ++t) {
    const int kv0 = t * 64;
    const bool haveK = (t + 1 < nt);

    // issue V(t) (Vbuf free: all PV(t-1) done at last barrier)
    gload16(vhb + (size_t)sr * 2048 + kv0 + sg, VH + wid * 512);
    gload16(vlb + (size_t)sr * 2048 + kv0 + sg, VL + wid * 512);
    // issue K(t+1) (buffer last read in QK^T(t-1), done at last barrier)
    if (haveK) {
      const int nb = (t + 1) & 1;
      const int nk = kv0 + 64;
      gload16(khb + (size_t)(nk + sr) * 64 + sg, KH[nb] + wid * 512);
      gload16(klb + (size_t)(nk + sr) * 64 + sg, KL[nb] + wid * 512);
      wait_vmcnt<4>();   // K(t) retired; V(t)+K(t+1) in flight
    } else {
      wait_vmcnt<2>();   // K(t) retired; V(t) in flight
    }
    syncb();             // K(t) visible to all waves

    const int cb = t & 1;
    const bool active = (kv0 <= q0w + 31);   // wave-uniform causal skip

    f32x4 sf[2][4];
    if (active) {
      const unsigned short* KHc = KH[cb];
      const unsigned short* KLc = KL[cb];

      // S = Q K^T (3-term split)
      #pragma unroll
      for (int mi = 0; mi < 2; mi++)
        #pragma unroll
        for (int ci = 0; ci < 4; ci++) sf[mi][ci] = (f32x4){0.f, 0.f, 0.f, 0.f};
      __builtin_amdgcn_s_setprio(1);
      #pragma unroll
      for (int ci = 0; ci < 4; ci++) {
        bf16x8 kh0 = *(const bf16x8*)(KHc + offK[ci][0]);
        bf16x8 kh1 = *(const bf16x8*)(KHc + offK[ci][1]);
        bf16x8 kl0 = *(const bf16x8*)(KLc + offK[ci][0]);
        bf16x8 kl1 = *(const bf16x8*)(KLc + offK[ci][1]);
        #pragma unroll
        for (int mi = 0; mi < 2; mi++) {
          f32x4 s = sf[mi][ci];
          s = __builtin_amdgcn_mfma_f32_16x16x32_bf16(qfh[mi][0], kh0, s, 0, 0, 0);
          s = __builtin_amdgcn_mfma_f32_16x16x32_bf16(qfh[mi][1], kh1, s, 0, 0, 0);
          s = __builtin_amdgcn_mfma_f32_16x16x32_bf16(qfh[mi][0], kl0, s, 0, 0, 0);
          s = __builtin_amdgcn_mfma_f32_16x16x32_bf16(qfh[mi][1], kl1, s, 0, 0, 0);
          s = __builtin_amdgcn_mfma_f32_16x16x32_bf16(qfl[mi][0], kh0, s, 0, 0, 0);
          s = __builtin_amdgcn_mfma_f32_16x16x32_bf16(qfl[mi][1], kh1, s, 0, 0, 0);
          sf[mi][ci] = s;
        }
      }
      __builtin_amdgcn_s_setprio(0);

      // causal mask on straddling tiles
      if (kv0 + 63 > q0w) {
        #pragma unroll
        for (int mi = 0; mi < 2; mi++)
          #pragma unroll
          for (int ci = 0; ci < 4; ci++)
            #pragma unroll
            for (int r = 0; r < 4; r++) {
              int q = q0w + mi * 16 + lg * 4 + r;
              int kv = kv0 + ci * 16 + lrow;
              if (kv > q) sf[mi][ci][r] = -1e30f;
            }
      }

      // online softmax (log2 domain), fp32 shfl reductions
      #pragma unroll
      for (int mi = 0; mi < 2; mi++)
        #pragma unroll
        for (int r = 0; r < 4; r++) {
          float mx = fmaxf(fmaxf(sf[mi][0][r], sf[mi][1][r]),
                           fmaxf(sf[mi][2][r], sf[mi][3][r]));
          mx = fmaxf(mx, __shfl_xor(mx, 1));
          mx = fmaxf(mx, __shfl_xor(mx, 2));
          mx = fmaxf(mx, __shfl_xor(mx, 4));
          mx = fmaxf(mx, __shfl_xor(mx, 8));
          float mn = fmaxf(m_[mi][r], mx);
          float alpha = __builtin_amdgcn_exp2f(m_[mi][r] - mn);
          m_[mi][r] = mn;
          float rs = 0.f;
          #pragma unroll
          for (int ci = 0; ci < 4; ci++) {
            float p = __builtin_amdgcn_exp2f(sf[mi][ci][r] - mn);
            sf[mi][ci][r] = p;
            rs += p;
          }
          rs += __shfl_xor(rs, 1);
          rs += __shfl_xor(rs, 2);
          rs += __shfl_xor(rs, 4);
          rs += __shfl_xor(rs, 8);
          l_[mi][r] = l_[mi][r] * alpha + rs;
          #pragma unroll
          for (int di = 0; di < 4; di++) oacc[mi][di][r] *= alpha;
        }

      // P -> wave-private LDS as bf16 (swizzled)
      #pragma unroll
      for (int mi = 0; mi < 2; mi++)
        #pragma unroll
        for (int ci = 0; ci < 4; ci++) {
          int colb = ci * 16 + lrow;
          int gcol = colb >> 3, crem = colb & 7;
          #pragma unroll
          for (int r = 0; r < 4; r++) {
            int rr = mi * 16 + lg * 4 + r;
            Pw[rr * 64 + ((gcol ^ (rr & 7)) * 8) + crem] = bf16_rn(sf[mi][ci][r]);
          }
        }
    }

    // V(t) resident (K(t+1) may still fly); publish to all waves
    if (haveK) wait_vmcnt<2>(); else wait_vmcnt<0>();
    syncb();

    if (active) {
      bf16x8 pa[2][2];
      #pragma unroll
      for (int mi = 0; mi < 2; mi++)
        #pragma unroll
        for (int ks = 0; ks < 2; ks++)
          pa[mi][ks] = *(const bf16x8*)(Pw + offP[mi][ks]);
      __builtin_amdgcn_s_setprio(1);
      #pragma unroll
      for (int di = 0; di < 4; di++) {
        bf16x8 vh0 = *(const bf16x8*)(VH + offK[di][0]);
        bf16x8 vh1 = *(const bf16x8*)(VH + offK[di][1]);
        bf16x8 vl0 = *(const bf16x8*)(VL + offK[di][0]);
        bf16x8 vl1 = *(const bf16x8*)(VL + offK[di][1]);
        #pragma unroll
        for (int mi = 0; mi < 2; mi++) {
          f32x4 o = oacc[mi][di];
          o = __builtin_amdgcn_mfma_f32_16x16x32_bf16(pa[mi][0], vh0, o, 0, 0, 0);
          o = __builtin_amdgcn_mfma_f32_16x16x32_bf16(pa[mi][1], vh1, o, 0, 0, 0);
          o = __builtin_amdgcn_mfma_f32_16x16x32_bf16(pa[mi][0], vl0, o, 0, 0, 0);
          o = __builtin_amdgcn_mfma_f32_16x16x32_bf16(pa[mi][1], vl1, o, 0, 0, 0);
          oacc[mi][di] = o;
        }
      }
      __builtin_amdgcn_s_setprio(0);
      asm volatile("s_waitcnt lgkmcnt(0)" ::: "memory");  // V reads landed
    }
    syncb();   // all waves done with Vbuf + K[cb] -> safe to overwrite next iter
  }

  // epilogue: normalize, write split-bf16 att [B*S][1024]
  #pragma unroll
  for (int mi = 0; mi < 2; mi++) {
    float inv[4];
    #pragma unroll
    for (int r = 0; r < 4; r++) inv[r] = 1.f / l_[mi][r];
    #pragma unroll
    for (int di = 0; di < 4; di++) {
      f32x4 o = oacc[mi][di];
      #pragma unroll
      for (int r = 0; r < 4; r++) {
        float v = o[r] * inv[r];
        int srow = q0w + mi * 16 + lg * 4 + r;
        size_t idx = ((size_t)b * Ss + srow) * 1024 + h * 64 + di * 16 + lrow;
        unsigned short hi = bf16_rn(v);
        atthi[idx] = hi;
        attlo[idx] = bf16_rn(v - bf16_f(hi));
      }
    }
  }
}

// ---------------------------------------------------------------------------
extern "C" void kernel_launch(void* const* d_in, const int* in_sizes, int n_in,
                              void* d_out, int out_size, void* d_ws, size_t ws_size,
                              hipStream_t stream) {
  const float* x    = (const float*)d_in[0];
  // d_in[1] = causal mask (hardcoded)
  const float* Wqkv = (const float*)d_in[2];
  const float* bqkv = (const float*)d_in[3];
  const float* Wout = (const float*)d_in[4];
  const float* bout = (const float*)d_in[5];
  float* out = (float*)d_out;

  char* ws = (char*)d_ws;
  unsigned short* Qh  = (unsigned short*)(ws);
  unsigned short* Ql  = (unsigned short*)(ws + 8388608);
  unsigned short* Kh  = (unsigned short*)(ws + 16777216);
  unsigned short* Kl  = (unsigned short*)(ws + 25165824);
  unsigned short* Vth = (unsigned short*)(ws + 33554432);
  unsigned short* Vtl = (unsigned short*)(ws + 41943040);
  unsigned short* atthi = (unsigned short*)(ws + 50331648);
  unsigned short* attlo = (unsigned short*)(ws + 58720256);
  unsigned short* xhi = (unsigned short*)(ws + 67108864);
  unsigned short* xlo = (unsigned short*)(ws + 75497472);
  unsigned short* wqh = (unsigned short*)(ws + 83886080);
  unsigned short* wql = (unsigned short*)(ws + 90177536);
  unsigned short* woh = (unsigned short*)(ws + 96468992);
  unsigned short* wol = (unsigned short*)(ws + 98566144);

  const int M = Bb * Ss;  // 4096

  split_f32<<<(M * Dd / 8) / 256, 256, 0, stream>>>(x, xhi, xlo, M * Dd / 8);
  transpose_split_f32<<<dim3(3 * Dd / 32, Dd / 32), 256, 0, stream>>>(Wqkv, wqh, wql, Dd, 3 * Dd);
  transpose_split_f32<<<dim3(Dd / 32, Dd / 32), 256, 0, stream>>>(Wout, woh, wol, Dd, Dd);

  // 1) QKV projection: 256x192 tile, counted-vmcnt pipeline, scatter epilogue
  gemm_qkv256<<<dim3(16, 16), 512, 0, stream>>>(
      xhi, xlo, wqh, wql, bqkv, Qh, Ql, Kh, Kl, Vth, Vtl);

  // 2) MFMA causal flash attention (pairing, K dbuf + V single-buf, 80KB LDS)
  flash_attn_mfma<<<dim3(Ss / 256, Hh, Bb), 512, 0, stream>>>(
      Qh, Ql, Kh, Kl, Vth, Vtl, atthi, attlo);

  // 3) output projection: 128x128 tile, 8 waves, counted-vmcnt pipeline
  gemm_out256<<<dim3(8, 32), 512, 0, stream>>>(
      atthi, attlo, woh, wol, bout, out);
}